// Round 2
// baseline (85.639 us; speedup 1.0000x reference)
//
#include <hip/hip_runtime.h>

#define NBINS 256
#define BATCH 4
#define NPIX  65536      // H*W per batch, C == 1
#define EPSF  1e-10f

// ---------------------------------------------------------------------------
// Pass 1: scatter-accumulate marginal histograms S1,S2 (per-batch 256 bins)
// and the joint histogram J (per-batch 256x256). Only the two nearest bins
// carry non-negligible Gaussian weight (sigma=0.1, bin spacing 1.0):
// third-nearest bin weight <= exp(-50) ~ 2e-22, i.e. < 1e-16 relative.
// ---------------------------------------------------------------------------
__global__ __launch_bounds__(256) void mi_accum(
    const float* __restrict__ in1, const float* __restrict__ in2,
    float* __restrict__ S1, float* __restrict__ S2, float* __restrict__ J)
{
    __shared__ float h1[NBINS];
    __shared__ float h2[NBINS];
    const int t = threadIdx.x;
    h1[t] = 0.0f;
    h2[t] = 0.0f;
    __syncthreads();

    const int pixPerBlock = 1024;                  // divides NPIX -> no batch straddle
    const int base = blockIdx.x * pixPerBlock;
    const int b = base / NPIX;
    float* __restrict__ Jb = J + (size_t)b * NBINS * NBINS;

#pragma unroll
    for (int i = 0; i < 4; ++i) {
        const int idx = base + i * 256 + t;
        const float v1 = in1[idx] * 255.0f;        // in [0,255)
        const float v2 = in2[idx] * 255.0f;
        const int k1 = (int)v1;                    // floor (v >= 0), k+1 <= 255
        const int k2 = (int)v2;
        const float d1 = v1 - (float)k1;
        const float d2 = v2 - (float)k2;
        const float e1 = 1.0f - d1;
        const float e2 = 1.0f - d2;
        const float w1a = expf(-50.0f * d1 * d1);  // bin k1   (residual d1)
        const float w1b = expf(-50.0f * e1 * e1);  // bin k1+1 (residual d1-1)
        const float w2a = expf(-50.0f * d2 * d2);
        const float w2b = expf(-50.0f * e2 * e2);

        atomicAdd(&h1[k1],     w1a);
        atomicAdd(&h1[k1 + 1], w1b);
        atomicAdd(&h2[k2],     w2a);
        atomicAdd(&h2[k2 + 1], w2b);

        float* Jr = Jb + k1 * NBINS + k2;
        atomicAdd(&Jr[0],         w1a * w2a);
        atomicAdd(&Jr[1],         w1a * w2b);
        atomicAdd(&Jr[NBINS],     w1b * w2a);
        atomicAdd(&Jr[NBINS + 1], w1b * w2b);
    }
    __syncthreads();

    atomicAdd(&S1[b * NBINS + t], h1[t]);
    atomicAdd(&S2[b * NBINS + t], h2[t]);
}

// ---------------------------------------------------------------------------
// Pass 2: one block per batch. Normalize pdfs / joint exactly like the
// reference (eps placement preserved), compute entropies, accumulate
// mean(2*MI/(H1+H2)) into *out.
// ---------------------------------------------------------------------------
__device__ __forceinline__ float block_reduce(float v, float* red)
{
    const int t = threadIdx.x;
    red[t] = v;
    __syncthreads();
    for (int s = 128; s > 0; s >>= 1) {
        if (t < s) red[t] += red[t + s];
        __syncthreads();
    }
    const float r = red[0];
    __syncthreads();
    return r;
}

__global__ __launch_bounds__(256) void mi_final(
    const float* __restrict__ S1, const float* __restrict__ S2,
    const float* __restrict__ J, float* __restrict__ out)
{
    __shared__ float red[256];
    const int b = blockIdx.x;
    const int t = threadIdx.x;
    const float invN = 1.0f / (float)NPIX;

    // H(x1)
    const float pre1 = S1[b * NBINS + t] * invN;           // pdf before norm
    const float sum1 = block_reduce(pre1, red);
    const float p1 = pre1 / (sum1 + EPSF);
    const float H1 = block_reduce(-p1 * log2f(p1 + EPSF), red);

    // H(x2)
    const float pre2 = S2[b * NBINS + t] * invN;
    const float sum2 = block_reduce(pre2, red);
    const float p2 = pre2 / (sum2 + EPSF);
    const float H2 = block_reduce(-p2 * log2f(p2 + EPSF), red);

    // H(x1,x2)
    const float* Jb = J + (size_t)b * NBINS * NBINS;
    float acc = 0.0f;
    for (int i = 0; i < NBINS; ++i) acc += Jb[i * NBINS + t];   // coalesced
    const float sumJ = block_reduce(acc, red);
    const float invD = 1.0f / (sumJ + EPSF);
    float hacc = 0.0f;
    for (int i = 0; i < NBINS; ++i) {
        const float p = Jb[i * NBINS + t] * invD;
        hacc += -p * log2f(p + EPSF);                           // p==0 -> 0
    }
    const float H12 = block_reduce(hacc, red);

    if (t == 0) {
        const float mi  = H1 + H2 - H12;
        const float nmi = 2.0f * mi / (H1 + H2);
        atomicAdd(out, nmi * (1.0f / (float)BATCH));
    }
}

// ---------------------------------------------------------------------------
extern "C" void kernel_launch(void* const* d_in, const int* in_sizes, int n_in,
                              void* d_out, int out_size, void* d_ws, size_t ws_size,
                              hipStream_t stream)
{
    const float* in1 = (const float*)d_in[0];
    const float* in2 = (const float*)d_in[1];

    float* S1 = (float*)d_ws;                          // BATCH*256
    float* S2 = S1 + BATCH * NBINS;                    // BATCH*256
    float* J  = S2 + BATCH * NBINS;                    // BATCH*256*256
    float* out = (float*)d_out;

    const size_t zero_bytes =
        (size_t)(2 * BATCH * NBINS + BATCH * NBINS * NBINS) * sizeof(float);
    (void)hipMemsetAsync(d_ws, 0, zero_bytes, stream);
    (void)hipMemsetAsync(d_out, 0, sizeof(float), stream);

    mi_accum<<<BATCH * NPIX / 1024, 256, 0, stream>>>(in1, in2, S1, S2, J);
    mi_final<<<BATCH, 256, 0, stream>>>(S1, S2, J, out);
}

// Round 3
// 60.170 us; speedup vs baseline: 1.4233x; 1.4233x over previous
//
#include <hip/hip_runtime.h>

#define NBINS  256
#define BATCH  4
#define NPIX   65536     // H*W per batch, C == 1
#define EPSF   1e-10f
#define RSTRIP 4         // joint rows owned per block
#define NSTRIP 64        // NBINS / RSTRIP

// ---------------------------------------------------------------------------
// Each block owns a RSTRIP-row strip of one batch's 256x256 joint histogram
// in LDS and scans the WHOLE batch (L2-resident re-reads), so the strip can
// be flushed with plain coalesced stores -- zero global atomics for J.
// Only the two nearest bins carry non-negligible Gaussian weight
// (sigma=0.1, spacing 1.0): third-nearest weight <= exp(-50) ~ 2e-22.
// Marginals: strip s owns pixel chunk [s*1024, s*1024+1024) (the vi>>8==s
// slice of the scan) -> LDS histogram + one global atomic per bin.
// ---------------------------------------------------------------------------
__global__ __launch_bounds__(1024) void mi_strip(
    const float* __restrict__ in1, const float* __restrict__ in2,
    float* __restrict__ S1, float* __restrict__ S2, float* __restrict__ J)
{
    __shared__ float js[RSTRIP * NBINS];   // 4 KB strip
    __shared__ float h1[NBINS];
    __shared__ float h2[NBINS];

    const int t  = threadIdx.x;            // 0..1023
    const int b  = blockIdx.x >> 6;        // / NSTRIP
    const int s  = blockIdx.x & (NSTRIP - 1);
    const int r0 = s * RSTRIP;

    js[t] = 0.0f;
    if (t < NBINS) { h1[t] = 0.0f; h2[t] = 0.0f; }
    __syncthreads();

    const float4* __restrict__ p1 = (const float4*)(in1 + b * NPIX);
    const float4* __restrict__ p2 = (const float4*)(in2 + b * NPIX);

    for (int it = 0; it < NPIX / 4096; ++it) {       // 16 iterations
        const int vi = it * 1024 + t;                // float4 index in batch
        const float4 a = p1[vi];
        const float4 c = p2[vi];
        const bool mflag = (vi >> 8) == s;           // marginal ownership

        const float vx1[4] = { a.x, a.y, a.z, a.w };
        const float vx2[4] = { c.x, c.y, c.z, c.w };
#pragma unroll
        for (int j = 0; j < 4; ++j) {
            const float v1 = vx1[j] * 255.0f;        // in [0,255)
            const float v2 = vx2[j] * 255.0f;
            const int k1 = (int)v1;                  // floor, k1 <= 254
            const int k2 = (int)v2;
            const unsigned u = (unsigned)(k1 - r0 + 1);   // <=4 -> strip hit
            if (mflag || u <= 4u) {
                const float d1 = v1 - (float)k1;
                const float d2 = v2 - (float)k2;
                const float e1 = 1.0f - d1;
                const float e2 = 1.0f - d2;
                const float w1a = expf(-50.0f * d1 * d1);  // bin k1
                const float w1b = expf(-50.0f * e1 * e1);  // bin k1+1
                const float w2a = expf(-50.0f * d2 * d2);
                const float w2b = expf(-50.0f * e2 * e2);
                if (u <= 4u) {
                    const int r = k1 - r0;                 // -1..3
                    if (r >= 0) {                          // row k1 in strip
                        atomicAdd(&js[r * NBINS + k2],     w1a * w2a);
                        atomicAdd(&js[r * NBINS + k2 + 1], w1a * w2b);
                    }
                    if (r < RSTRIP - 1) {                  // row k1+1 in strip
                        atomicAdd(&js[(r + 1) * NBINS + k2],     w1b * w2a);
                        atomicAdd(&js[(r + 1) * NBINS + k2 + 1], w1b * w2b);
                    }
                }
                if (mflag) {
                    atomicAdd(&h1[k1],     w1a);
                    atomicAdd(&h1[k1 + 1], w1b);
                    atomicAdd(&h2[k2],     w2a);
                    atomicAdd(&h2[k2 + 1], w2b);
                }
            }
        }
    }
    __syncthreads();

    // strip rows r0..r0+3 are contiguous in J -> one coalesced store/thread
    J[((size_t)b * NBINS + r0) * NBINS + t] = js[t];
    if (t < NBINS) {
        atomicAdd(&S1[b * NBINS + t], h1[t]);
        atomicAdd(&S2[b * NBINS + t], h2[t]);
    }
}

// ---------------------------------------------------------------------------
// One block per batch, 1024 threads. Reproduces the reference's eps
// placement exactly; accumulates mean(2*MI/(H1+H2)) into *out.
// ---------------------------------------------------------------------------
__device__ __forceinline__ float block_reduce(float v, float* red)
{
    const int t = threadIdx.x;
    red[t] = v;
    __syncthreads();
    for (int s = 512; s > 0; s >>= 1) {
        if (t < s) red[t] += red[t + s];
        __syncthreads();
    }
    const float r = red[0];
    __syncthreads();
    return r;
}

__global__ __launch_bounds__(1024) void mi_final(
    const float* __restrict__ S1, const float* __restrict__ S2,
    const float* __restrict__ J, float* __restrict__ out)
{
    __shared__ float red[1024];
    const int b = blockIdx.x;
    const int t = threadIdx.x;
    const float invN = 1.0f / (float)NPIX;

    // H(x1)
    const float pre1 = (t < NBINS) ? S1[b * NBINS + t] * invN : 0.0f;
    const float sum1 = block_reduce(pre1, red);
    const float p1 = pre1 / (sum1 + EPSF);
    const float H1 = block_reduce((t < NBINS) ? -p1 * log2f(p1 + EPSF) : 0.0f, red);

    // H(x2)
    const float pre2 = (t < NBINS) ? S2[b * NBINS + t] * invN : 0.0f;
    const float sum2 = block_reduce(pre2, red);
    const float p2 = pre2 / (sum2 + EPSF);
    const float H2 = block_reduce((t < NBINS) ? -p2 * log2f(p2 + EPSF) : 0.0f, red);

    // H(x1,x2): thread handles column (t&255), rows q*64..q*64+63
    const float* __restrict__ Jb = J + (size_t)b * NBINS * NBINS;
    const int col = t & (NBINS - 1);
    const int q = t >> 8;
    float acc = 0.0f;
    for (int k = 0; k < 64; ++k) acc += Jb[(q * 64 + k) * NBINS + col];
    const float sumJ = block_reduce(acc, red);
    const float invD = 1.0f / (sumJ + EPSF);
    float hacc = 0.0f;
    for (int k = 0; k < 64; ++k) {
        const float p = Jb[(q * 64 + k) * NBINS + col] * invD;
        hacc += -p * log2f(p + EPSF);
    }
    const float H12 = block_reduce(hacc, red);

    if (t == 0) {
        const float mi  = H1 + H2 - H12;
        const float nmi = 2.0f * mi / (H1 + H2);
        atomicAdd(out, nmi * (1.0f / (float)BATCH));
    }
}

// ---------------------------------------------------------------------------
extern "C" void kernel_launch(void* const* d_in, const int* in_sizes, int n_in,
                              void* d_out, int out_size, void* d_ws, size_t ws_size,
                              hipStream_t stream)
{
    const float* in1 = (const float*)d_in[0];
    const float* in2 = (const float*)d_in[1];

    float* S1  = (float*)d_ws;                     // BATCH*256
    float* S2  = S1 + BATCH * NBINS;               // BATCH*256
    float* J   = S2 + BATCH * NBINS;               // BATCH*256*256 (fully overwritten)
    float* out = (float*)d_out;

    (void)hipMemsetAsync(d_ws, 0, (size_t)(2 * BATCH * NBINS) * sizeof(float), stream);
    (void)hipMemsetAsync(d_out, 0, sizeof(float), stream);

    mi_strip<<<BATCH * NSTRIP, 1024, 0, stream>>>(in1, in2, S1, S2, J);
    mi_final<<<BATCH, 1024, 0, stream>>>(S1, S2, J, out);
}

// Round 4
// 55.864 us; speedup vs baseline: 1.5330x; 1.0771x over previous
//
#include <hip/hip_runtime.h>

#define NBINS  256
#define BATCH  4
#define NPIX   65536     // H*W per batch, C == 1
#define EPSF   1e-10f
#define RSTRIP 4         // joint rows owned per block
#define NSTRIP 64        // NBINS / RSTRIP

// ---------------------------------------------------------------------------
// Each block owns a RSTRIP-row strip of one batch's 256x256 joint histogram
// in LDS and scans the WHOLE batch (L2-resident re-reads), so the strip is
// flushed with plain coalesced stores -- zero global atomics for J.
// Only the two nearest bins carry non-negligible Gaussian weight
// (sigma=0.1, spacing 1.0): third-nearest weight <= exp(-50) ~ 2e-22.
// Marginals: strip s owns pixel chunk [s*1024, s*1024+1024) (the vi>>8==s
// slice of the scan); partial histograms are STORED (not atomically merged)
// to S1part/S2part and summed in mi_final -> no global atomics, no memset.
// d_out is zeroed by block 0 here (stream-ordered before mi_final's adds).
// ---------------------------------------------------------------------------
__global__ __launch_bounds__(1024) void mi_strip(
    const float* __restrict__ in1, const float* __restrict__ in2,
    float* __restrict__ S1part, float* __restrict__ S2part,
    float* __restrict__ J, float* __restrict__ out)
{
    __shared__ float js[RSTRIP * NBINS];   // 4 KB strip
    __shared__ float h1[NBINS];
    __shared__ float h2[NBINS];

    const int t  = threadIdx.x;            // 0..1023
    const int b  = blockIdx.x >> 6;        // / NSTRIP
    const int s  = blockIdx.x & (NSTRIP - 1);
    const int r0 = s * RSTRIP;

    if (blockIdx.x == 0 && t == 0) *out = 0.0f;   // graph-replay re-init

    js[t] = 0.0f;
    if (t < NBINS) { h1[t] = 0.0f; h2[t] = 0.0f; }
    __syncthreads();

    const float4* __restrict__ p1 = (const float4*)(in1 + b * NPIX);
    const float4* __restrict__ p2 = (const float4*)(in2 + b * NPIX);

    for (int it = 0; it < NPIX / 4096; ++it) {       // 16 iterations
        const int vi = it * 1024 + t;                // float4 index in batch
        const float4 a = p1[vi];
        const float4 c = p2[vi];
        const bool mflag = (vi >> 8) == s;           // marginal ownership

        const float vx1[4] = { a.x, a.y, a.z, a.w };
        const float vx2[4] = { c.x, c.y, c.z, c.w };
#pragma unroll
        for (int j = 0; j < 4; ++j) {
            const float v1 = vx1[j] * 255.0f;        // in [0,255)
            const float v2 = vx2[j] * 255.0f;
            const int k1 = (int)v1;                  // floor, k1 <= 254
            const int k2 = (int)v2;
            const unsigned u = (unsigned)(k1 - r0 + 1);   // <=4 -> strip hit
            if (mflag || u <= 4u) {
                const float d1 = v1 - (float)k1;
                const float d2 = v2 - (float)k2;
                const float e1 = 1.0f - d1;
                const float e2 = 1.0f - d2;
                const float w1a = expf(-50.0f * d1 * d1);  // bin k1
                const float w1b = expf(-50.0f * e1 * e1);  // bin k1+1
                const float w2a = expf(-50.0f * d2 * d2);
                const float w2b = expf(-50.0f * e2 * e2);
                if (u <= 4u) {
                    const int r = k1 - r0;                 // -1..3
                    if (r >= 0) {                          // row k1 in strip
                        atomicAdd(&js[r * NBINS + k2],     w1a * w2a);
                        atomicAdd(&js[r * NBINS + k2 + 1], w1a * w2b);
                    }
                    if (r < RSTRIP - 1) {                  // row k1+1 in strip
                        atomicAdd(&js[(r + 1) * NBINS + k2],     w1b * w2a);
                        atomicAdd(&js[(r + 1) * NBINS + k2 + 1], w1b * w2b);
                    }
                }
                if (mflag) {
                    atomicAdd(&h1[k1],     w1a);
                    atomicAdd(&h1[k1 + 1], w1b);
                    atomicAdd(&h2[k2],     w2a);
                    atomicAdd(&h2[k2 + 1], w2b);
                }
            }
        }
    }
    __syncthreads();

    // strip rows r0..r0+3 are contiguous in J -> one coalesced store/thread
    J[((size_t)b * NBINS + r0) * NBINS + t] = js[t];
    if (t < NBINS) {
        S1part[((size_t)b * NSTRIP + s) * NBINS + t] = h1[t];
        S2part[((size_t)b * NSTRIP + s) * NBINS + t] = h2[t];
    }
}

// ---------------------------------------------------------------------------
// One block per batch, 1024 threads. Sums the 64 marginal partials, then
// reproduces the reference's eps placement exactly; accumulates
// mean(2*MI/(H1+H2)) into *out (zeroed by mi_strip).
// ---------------------------------------------------------------------------
__device__ __forceinline__ float block_reduce(float v, float* red)
{
    const int t = threadIdx.x;
    red[t] = v;
    __syncthreads();
    for (int s = 512; s > 0; s >>= 1) {
        if (t < s) red[t] += red[t + s];
        __syncthreads();
    }
    const float r = red[0];
    __syncthreads();
    return r;
}

__global__ __launch_bounds__(1024) void mi_final(
    const float* __restrict__ S1part, const float* __restrict__ S2part,
    const float* __restrict__ J, float* __restrict__ out)
{
    __shared__ float red[1024];
    const int b = blockIdx.x;
    const int t = threadIdx.x;
    const float invN = 1.0f / (float)NPIX;

    // Sum the 64 per-strip marginal partials (coalesced across t)
    float pre1 = 0.0f, pre2 = 0.0f;
    if (t < NBINS) {
        const float* __restrict__ q1 = S1part + (size_t)b * NSTRIP * NBINS + t;
        const float* __restrict__ q2 = S2part + (size_t)b * NSTRIP * NBINS + t;
        float a1 = 0.0f, a2 = 0.0f;
#pragma unroll 8
        for (int s = 0; s < NSTRIP; ++s) {
            a1 += q1[s * NBINS];
            a2 += q2[s * NBINS];
        }
        pre1 = a1 * invN;
        pre2 = a2 * invN;
    }

    // H(x1)
    const float sum1 = block_reduce(pre1, red);
    const float p1 = pre1 / (sum1 + EPSF);
    const float H1 = block_reduce((t < NBINS) ? -p1 * log2f(p1 + EPSF) : 0.0f, red);

    // H(x2)
    const float sum2 = block_reduce(pre2, red);
    const float p2 = pre2 / (sum2 + EPSF);
    const float H2 = block_reduce((t < NBINS) ? -p2 * log2f(p2 + EPSF) : 0.0f, red);

    // H(x1,x2): thread handles column (t&255), rows q*64..q*64+63
    const float* __restrict__ Jb = J + (size_t)b * NBINS * NBINS;
    const int col = t & (NBINS - 1);
    const int q = t >> 8;
    float acc = 0.0f;
    for (int k = 0; k < 64; ++k) acc += Jb[(q * 64 + k) * NBINS + col];
    const float sumJ = block_reduce(acc, red);
    const float invD = 1.0f / (sumJ + EPSF);
    float hacc = 0.0f;
    for (int k = 0; k < 64; ++k) {
        const float p = Jb[(q * 64 + k) * NBINS + col] * invD;
        hacc += -p * log2f(p + EPSF);
    }
    const float H12 = block_reduce(hacc, red);

    if (t == 0) {
        const float mi  = H1 + H2 - H12;
        const float nmi = 2.0f * mi / (H1 + H2);
        atomicAdd(out, nmi * (1.0f / (float)BATCH));
    }
}

// ---------------------------------------------------------------------------
extern "C" void kernel_launch(void* const* d_in, const int* in_sizes, int n_in,
                              void* d_out, int out_size, void* d_ws, size_t ws_size,
                              hipStream_t stream)
{
    const float* in1 = (const float*)d_in[0];
    const float* in2 = (const float*)d_in[1];

    float* S1part = (float*)d_ws;                              // BATCH*64*256
    float* S2part = S1part + BATCH * NSTRIP * NBINS;           // BATCH*64*256
    float* J      = S2part + BATCH * NSTRIP * NBINS;           // BATCH*256*256
    float* out    = (float*)d_out;

    // All workspace regions are fully overwritten each call -> no memsets,
    // graph has exactly two kernel nodes.
    mi_strip<<<BATCH * NSTRIP, 1024, 0, stream>>>(in1, in2, S1part, S2part, J, out);
    mi_final<<<BATCH, 1024, 0, stream>>>(S1part, S2part, J, out);
}

// Round 6
// 35.810 us; speedup vs baseline: 2.3915x; 1.5600x over previous
//
#include <hip/hip_runtime.h>

#define NBINS  256
#define BATCH  4
#define NPIX   65536     // H*W per batch, C == 1
#define EPSF   1e-10f
#define RSTRIP 16        // joint rows owned per block
#define NSTRIP 16        // NBINS / RSTRIP
#define NQ     4         // scan quarters
#define QPIX   (NPIX / NQ)   // 16384 pixels

// ---------------------------------------------------------------------------
// mi_strip: block (b, s, q) scans quarter q of batch b, accumulating rows
// [16s, 16s+16) of the joint histogram in LDS, flushed with plain stores to
// quarter-partial images Jpart[b][q]. Only the two nearest bins carry
// non-negligible Gaussian weight (sigma=0.1, spacing 1.0; 3rd bin ~ exp(-50)).
// Weights are computed unconditionally (hit rate 6.6% -> ~99% of wave-steps
// would enter a branchy path anyway); __expf is the 2-instr fast exp.
// Marginals: (s,q) owns the l>>8==s slice of its quarter -> each pixel
// counted exactly once; partials stored (no global atomics, no memsets).
// ---------------------------------------------------------------------------
__global__ __launch_bounds__(1024) void mi_strip(
    const float* __restrict__ in1, const float* __restrict__ in2,
    float* __restrict__ S1part, float* __restrict__ S2part,
    float* __restrict__ Jpart)
{
    __shared__ float js[RSTRIP * NBINS];   // 16 KB
    __shared__ float h1[NBINS];
    __shared__ float h2[NBINS];

    const int t  = threadIdx.x;            // 0..1023
    const int b  = blockIdx.x >> 6;
    const int s  = (blockIdx.x >> 2) & (NSTRIP - 1);
    const int q  = blockIdx.x & (NQ - 1);
    const int r0 = s << 4;

#pragma unroll
    for (int i = 0; i < 4; ++i) js[(i << 10) + t] = 0.0f;
    if (t < NBINS) { h1[t] = 0.0f; h2[t] = 0.0f; }
    __syncthreads();

    const float4* __restrict__ p1 = (const float4*)(in1 + b * NPIX) + q * (QPIX / 4);
    const float4* __restrict__ p2 = (const float4*)(in2 + b * NPIX) + q * (QPIX / 4);

#pragma unroll
    for (int it = 0; it < QPIX / 4096; ++it) {   // 4 iterations
        const int l = (it << 10) + t;            // float4 idx in quarter [0,4096)
        const float4 a = p1[l];
        const float4 c = p2[l];
        const bool mflag = (l >> 8) == s;        // marginal ownership (1/16 slice)

        const float vx1[4] = { a.x, a.y, a.z, a.w };
        const float vx2[4] = { c.x, c.y, c.z, c.w };
#pragma unroll
        for (int j = 0; j < 4; ++j) {
            const float v1 = vx1[j] * 255.0f;    // in [0,255)
            const float v2 = vx2[j] * 255.0f;
            const int k1 = (int)v1;              // floor, <= 254
            const int k2 = (int)v2;
            const float d1 = v1 - (float)k1;
            const float d2 = v2 - (float)k2;
            const float e1 = d1 - 1.0f;          // residual of bin k1+1
            const float e2 = d2 - 1.0f;
            const float w1a = __expf(-50.0f * d1 * d1);
            const float w1b = __expf(-50.0f * e1 * e1);
            const float w2a = __expf(-50.0f * d2 * d2);
            const float w2b = __expf(-50.0f * e2 * e2);

            const int r = k1 - r0;
            if ((unsigned)r < RSTRIP) {          // row k1 in strip
                atomicAdd(&js[(r << 8) + k2],     w1a * w2a);
                atomicAdd(&js[(r << 8) + k2 + 1], w1a * w2b);
            }
            if ((unsigned)(r + 1) < RSTRIP) {    // row k1+1 in strip
                atomicAdd(&js[((r + 1) << 8) + k2],     w1b * w2a);
                atomicAdd(&js[((r + 1) << 8) + k2 + 1], w1b * w2b);
            }
            if (mflag) {
                atomicAdd(&h1[k1],     w1a);
                atomicAdd(&h1[k1 + 1], w1b);
                atomicAdd(&h2[k2],     w2a);
                atomicAdd(&h2[k2 + 1], w2b);
            }
        }
    }
    __syncthreads();

    // flush strip rows (contiguous in the quarter image) with coalesced stores
    float* __restrict__ Jq = Jpart + ((size_t)(b * NQ + q) << 16) + (r0 << 8);
#pragma unroll
    for (int i = 0; i < 4; ++i) {
        const int idx = (i << 10) + t;
        Jq[idx] = js[idx];
    }
    if (t < NBINS) {
        const size_t po = (size_t)(((b * NSTRIP + s) * NQ + q)) << 8;
        S1part[po + t] = h1[t];
        S2part[po + t] = h2[t];
    }
}

// ---------------------------------------------------------------------------
// mi_entrop: 16 blocks (b, g). Merges the 4 quarter-partials on the fly for
// 64 joint rows and reduces S = sum(c), T = sum(c*log2(c)) -- both LINEAR in
// c, so no global pre-normalization pass is needed. H12 is reconstructed in
// mi_combine via H12 = log2(S+eps)*S/(S+eps) - T/(S+eps)  (the reference's
// eps-inside-log differs by ~65536*eps/ln2 ~ 1e-5 bits: negligible).
// NOTE: cells can hold DENORMAL masses (tap products down to ~4e-44);
// v_log_f32 flushes denormal inputs -> -inf -> NaN under FTZ multiply
// (round-5 failure). Guard at 1e-30: discarded |c*log2 c| < 1e-28, harmless.
// ---------------------------------------------------------------------------
__global__ __launch_bounds__(1024) void mi_entrop(
    const float* __restrict__ Jpart, float* __restrict__ SJ, float* __restrict__ TJ)
{
    __shared__ float red[1024];
    const int t   = threadIdx.x;
    const int b   = blockIdx.x >> 2;
    const int g   = blockIdx.x & 3;        // 64-row group
    const int col = t & (NBINS - 1);
    const int ro  = t >> 8;                // 0..3
    const float* __restrict__ J0 = Jpart + ((size_t)(b * NQ) << 16);

    float Sacc = 0.0f, Tacc = 0.0f;
#pragma unroll 4
    for (int k = 0; k < 16; ++k) {
        const int row = (g << 6) + (ro << 4) + k;
        const size_t off = ((size_t)row << 8) + col;
        const float c = J0[off] + J0[off + (1 << 16)]
                      + J0[off + (2 << 16)] + J0[off + (3 << 16)];
        Sacc += c;
        Tacc += (c > 1e-30f) ? c * __log2f(c) : 0.0f;
    }
    red[t] = Sacc; __syncthreads();
    for (int s = 512; s > 0; s >>= 1) { if (t < s) red[t] += red[t + s]; __syncthreads(); }
    const float Stot = red[0]; __syncthreads();
    red[t] = Tacc; __syncthreads();
    for (int s = 512; s > 0; s >>= 1) { if (t < s) red[t] += red[t + s]; __syncthreads(); }
    if (t == 0) { SJ[blockIdx.x] = Stot; TJ[blockIdx.x] = red[0]; }
}

// ---------------------------------------------------------------------------
// mi_combine: one block, 4 batch-segments of 256 threads. Sums the 64
// marginal partials per bin, reproduces the reference's marginal-entropy eps
// placement exactly, reconstructs H12 from (SJ, TJ), and writes the mean
// normalized MI with a single plain store (overwrites poisoned d_out).
// ---------------------------------------------------------------------------
__global__ __launch_bounds__(1024) void mi_combine(
    const float* __restrict__ S1part, const float* __restrict__ S2part,
    const float* __restrict__ SJ, const float* __restrict__ TJ,
    float* __restrict__ out)
{
    __shared__ float red[1024];
    __shared__ float nmi[BATCH];
    const int t   = threadIdx.x;
    const int b   = t >> 8;                // batch segment
    const int bin = t & (NBINS - 1);
    const float invN = 1.0f / (float)NPIX;

    // merge 64 marginal partials per (b, bin)
    const float* __restrict__ q1 = S1part + ((size_t)b << 14) + bin;
    const float* __restrict__ q2 = S2part + ((size_t)b << 14) + bin;
    float a1 = 0.0f, a2 = 0.0f;
#pragma unroll 8
    for (int j = 0; j < 64; ++j) { a1 += q1[(size_t)j << 8]; a2 += q2[(size_t)j << 8]; }
    const float pre1 = a1 * invN;
    const float pre2 = a2 * invN;

    // segmented (per-256) reduction; returns segment sum to every thread
    auto segreduce = [&](float v) -> float {
        red[t] = v; __syncthreads();
        for (int s = 128; s > 0; s >>= 1) {
            if (bin < s) red[t] += red[t + s];
            __syncthreads();
        }
        const float r = red[b << 8];
        __syncthreads();
        return r;
    };

    const float sum1 = segreduce(pre1);
    const float p1 = pre1 / (sum1 + EPSF);
    const float H1 = segreduce(-p1 * __log2f(p1 + EPSF));

    const float sum2 = segreduce(pre2);
    const float p2 = pre2 / (sum2 + EPSF);
    const float H2 = segreduce(-p2 * __log2f(p2 + EPSF));

    const float SJb = SJ[b << 2] + SJ[(b << 2) + 1] + SJ[(b << 2) + 2] + SJ[(b << 2) + 3];
    const float TJb = TJ[b << 2] + TJ[(b << 2) + 1] + TJ[(b << 2) + 2] + TJ[(b << 2) + 3];
    const float Sp  = SJb + EPSF;
    const float H12 = __log2f(Sp) * (SJb / Sp) - TJb / Sp;

    if (bin == 0) {
        const float mi = H1 + H2 - H12;
        nmi[b] = 2.0f * mi / (H1 + H2);
    }
    __syncthreads();
    if (t == 0) *out = 0.25f * (nmi[0] + nmi[1] + nmi[2] + nmi[3]);
}

// ---------------------------------------------------------------------------
extern "C" void kernel_launch(void* const* d_in, const int* in_sizes, int n_in,
                              void* d_out, int out_size, void* d_ws, size_t ws_size,
                              hipStream_t stream)
{
    const float* in1 = (const float*)d_in[0];
    const float* in2 = (const float*)d_in[1];

    float* S1part = (float*)d_ws;                                   // 4*64*256
    float* S2part = S1part + BATCH * NSTRIP * NQ * NBINS;           // 4*64*256
    float* Jpart  = S2part + BATCH * NSTRIP * NQ * NBINS;           // 4*4*256*256
    float* SJ     = Jpart + (size_t)BATCH * NQ * NBINS * NBINS;     // 16
    float* TJ     = SJ + BATCH * NQ;                                // 16
    float* out    = (float*)d_out;

    // All workspace regions fully overwritten each call -> no memset nodes.
    mi_strip<<<BATCH * NSTRIP * NQ, 1024, 0, stream>>>(in1, in2, S1part, S2part, Jpart);
    mi_entrop<<<BATCH * NQ, 1024, 0, stream>>>(Jpart, SJ, TJ);
    mi_combine<<<1, 1024, 0, stream>>>(S1part, S2part, SJ, TJ, out);
}